// Round 11
// baseline (34.201 us; speedup 1.0000x reference)
//
#include <hip/hip_runtime.h>

// Problem constants (from reference)
#define BATCH 16
#define NSEG 32
#define HW (512 * 1024)              // 524288 pixels per batch
#define MIN_PIX 50.0f

// Accum: 1-wave blocks, per-thread f32x4 bins in LDS, serial RMW (R3 champion
// inner loop verbatim), 4-deep global prefetch, atomic tail into 8 KB acc.
// 1024 blocks @ 32 KiB = 4 blocks/CU resident in ONE scheduling round.
#define THREADS 64
#define CHUNKS 64                    // blocks per batch -> 1024 blocks total
#define QUADS 32                     // 8192 px/block / (64 thr * 4 px)

// Accumulator layout in d_ws: acc[b][s][4], comp: 0=cnt 1=su 2=sv 3=s2
#define ACC_FLOATS (BATCH * NSEG * 4)

__global__ __launch_bounds__(THREADS) void ovl_accum(
    const float* __restrict__ flow,   // [B, 2, H, W]
    const int* __restrict__ masks,    // [B, H, W]
    float* __restrict__ acc)          // [B, S, 4], pre-zeroed
{
    __shared__ float4 bins[THREADS][NSEG];   // 32 KiB

    const int tid = threadIdx.x;
    #pragma unroll
    for (int i = 0; i < NSEG; ++i)
        bins[tid][i] = make_float4(0.0f, 0.0f, 0.0f, 0.0f);
    // single wave per block: lockstep, no barrier needed

    const int bid = blockIdx.x;
    const int b  = bid >> 6;                 // batch
    const int bk = bid & (CHUNKS - 1);       // block within batch
    const float* __restrict__ u_base = flow + (size_t)b * 2 * HW;
    const float* __restrict__ v_base = u_base + HW;
    const int*   __restrict__ m_base = masks + (size_t)b * HW;

#define LOADP(S, Q) { const int p = (((Q) * CHUNKS + bk) * THREADS + tid) * 4; \
        m##S = *(const int4*)(m_base + p);                                     \
        u##S = *(const float4*)(u_base + p);                                   \
        v##S = *(const float4*)(v_base + p); }

// One pixel: minimal serial b128 RMW (R3 structure — fastest measured).
#define PX(mm, uu, vv) {                                                    \
        const int   s  = (mm) & (NSEG - 1);                                 \
        const float u_ = (uu), v_ = (vv);                                   \
        float4 cur = bins[tid][s];                                          \
        cur.x += 1.0f;                                                      \
        cur.y += u_;                                                        \
        cur.z += v_;                                                        \
        cur.w += fmaf(u_, u_, v_ * v_);                                     \
        bins[tid][s] = cur;                                                 \
    }

#define PROCQ(mq, uq, vq) { PX(mq.x, uq.x, vq.x) PX(mq.y, uq.y, vq.y)       \
                            PX(mq.z, uq.z, vq.z) PX(mq.w, uq.w, vq.w) }

    int4 mA, mB, mC, mD; float4 uA, vA, uB, vB, uC, vC, uD, vD;
    LOADP(A, 0)
    LOADP(B, 1)
    LOADP(C, 2)
    LOADP(D, 3)
    #pragma unroll
    for (int q = 0; q < QUADS; q += 4) {
        PROCQ(mA, uA, vA)
        if (q + 4 < QUADS) LOADP(A, q + 4)
        PROCQ(mB, uB, vB)
        if (q + 5 < QUADS) LOADP(B, q + 5)
        PROCQ(mC, uC, vC)
        if (q + 6 < QUADS) LOADP(C, q + 6)
        PROCQ(mD, uD, vD)
        if (q + 7 < QUADS) LOADP(D, q + 7)
    }

    __syncthreads();

    // Reduce the 64 private rows -> one native global fp32 atomic per
    // (seg,comp) pair (128 per block, 2048 distinct addresses total).
    const float* bf = (const float*)bins;    // [64][128] floats
    #pragma unroll
    for (int h = 0; h < 2; ++h) {
        const int pair = tid + h * 64;       // 0..127 = s*4 + c
        float sum = 0.0f;
        #pragma unroll
        for (int j = 0; j < THREADS; ++j)
            sum += bf[j * (NSEG * 4) + pair];
        unsafeAtomicAdd(&acc[(size_t)b * NSEG * 4 + pair], sum);
    }
}

__global__ __launch_bounds__(BATCH * NSEG) void ovl_finalize(
    const float* __restrict__ acc,   // [B*S, 4]
    float* __restrict__ out)         // scalar
{
    const int tid = threadIdx.x;     // 0..511, one per global segment id
    const float cnt = acc[tid * 4 + 0];
    const float su  = acc[tid * 4 + 1];
    const float sv  = acc[tid * 4 + 2];
    const float s2  = acc[tid * 4 + 3];

    const bool is_bg = (tid & (NSEG - 1)) == 0;
    const bool valid = (cnt >= MIN_PIX) && !is_bg;

    const float safe_cnt = fmaxf(cnt, 1.0f);
    const float denom = fmaxf(cnt - 1.0f, 1.0f);
    const float var_sum = (s2 - (su * su + sv * sv) / safe_cnt) / denom;

    float t = valid ? var_sum : 0.0f;
    float n = valid ? 1.0f : 0.0f;

    #pragma unroll
    for (int off = 32; off >= 1; off >>= 1) {
        t += __shfl_down(t, off, 64);
        n += __shfl_down(n, off, 64);
    }

    __shared__ float st[8], sn[8];
    const int wave = tid >> 6;
    const int lane = tid & 63;
    if (lane == 0) { st[wave] = t; sn[wave] = n; }
    __syncthreads();

    if (tid == 0) {
        float tot = 0.0f, ntot = 0.0f;
        #pragma unroll
        for (int w = 0; w < 8; ++w) { tot += st[w]; ntot += sn[w]; }
        out[0] = (ntot > 0.0f) ? (tot / fmaxf(ntot, 1.0f)) : 0.0f;
    }
}

extern "C" void kernel_launch(void* const* d_in, const int* in_sizes, int n_in,
                              void* d_out, int out_size, void* d_ws, size_t ws_size,
                              hipStream_t stream) {
    const float* flow = (const float*)d_in[0];
    const int* masks  = (const int*)d_in[1];
    float* out = (float*)d_out;
    float* acc = (float*)d_ws;

    hipMemsetAsync(acc, 0, ACC_FLOATS * sizeof(float), stream);

    ovl_accum<<<BATCH * CHUNKS, THREADS, 0, stream>>>(flow, masks, acc);
    ovl_finalize<<<1, BATCH * NSEG, 0, stream>>>(acc, out);
}